// Round 5
// baseline (61.196 us; speedup 1.0000x reference)
//
#include <hip/hip_runtime.h>
#include <math.h>

#define DIM 512
#define BATCH 1024
#define NPAIR (DIM * (DIM - 1) / 2)

typedef short bf16x8 __attribute__((ext_vector_type(8)));
typedef float f32x4  __attribute__((ext_vector_type(4)));

// ---- bf16 split helpers (RTN-even) ----
__device__ __forceinline__ unsigned short f2bf(float f) {
    unsigned int u = __float_as_uint(f);
    u += 0x7fff + ((u >> 16) & 1);
    return (unsigned short)(u >> 16);
}
__device__ __forceinline__ float bf2f(unsigned short h) {
    return __uint_as_float(((unsigned int)h) << 16);
}

// ws byte layout:
//   Mh      @ 0        : ushort[512*512]  (512 KB)
//   Ml      @ 512 KB   : ushort[512*512]  (512 KB)
//   partial @ 1 MB     : float[64][1024]  (256 KB)   slot = (n_blk*2+wn)*8 + kspl
//   cnt     @ 1.25 MB  : int[16]          (per-m_blk arrival tickets)
#define ML_BYTE   (512u * 1024u)
#define PART_BYTE (1024u * 1024u)
#define CNT_BYTE  (1024u * 1024u + 256u * 1024u)

// ---------------- kernel 1: prep (M triangle->dense hi/lo + zero tickets) ----------------
#define NT 16
__global__ __launch_bounds__(256)
void prep(const float* __restrict__ W,
          unsigned short* __restrict__ Mh, unsigned short* __restrict__ Ml,
          int* __restrict__ cnt) {
    const int bid = blockIdx.x;
    if (bid == 136) {                       // ticket reset (runs before gemm in stream order)
        if (threadIdx.x < 16) cnt[threadIdx.x] = 0;
        return;
    }
    // map bid -> (ti, tj), ti <= tj
    int ti = 0, base = 0;
    while (base + (NT - ti) <= bid) { base += NT - ti; ++ti; }
    const int tj = ti + (bid - base);
    const int tx = threadIdx.x & 31, ty8 = threadIdx.x >> 5;
    const int i0 = ti * 32, j0 = tj * 32;
    const float* Wp  = W + DIM;
    const float* Wsq = W + DIM + NPAIR;
    __shared__ float ld[32][33];
    #pragma unroll
    for (int s = 0; s < 4; ++s) {
        const int iy = ty8 + s * 8;
        const int i = i0 + iy, j = j0 + tx;
        float v = 0.f;
        if (j > i)       v = 0.5f * Wp[i * (DIM - 2) - (i * (i - 1)) / 2 - 1 + j];
        else if (j == i) v = Wsq[i];
        ld[iy][tx] = v;
        if (j >= i) {
            unsigned short h = f2bf(v);
            Mh[i * DIM + j] = h;
            Ml[i * DIM + j] = f2bf(v - bf2f(h));
        }
    }
    __syncthreads();
    #pragma unroll
    for (int s = 0; s < 4; ++s) {
        const int a = ty8 + s * 8;
        const int jj = j0 + a, ii = i0 + tx;
        if (jj > ii) {
            float v = ld[tx][a];
            unsigned short h = f2bf(v);
            Mh[jj * DIM + ii] = h;
            Ml[jj * DIM + ii] = f2bf(v - bf2f(h));
        }
    }
}

// ---------------- kernel 2: bf16-split MFMA GEMM + in-kernel A-convert + split-K fan-in ----
// grid 512 = 16 m_blk x 4 n_blk x 8 kspl ; block 256 thr = 4 waves (2 wm x 2 wn)
// block tile: 64 m x 128 n x 64 k ; wave: 32m x 64n (2 sm x 4 sn of 16x16) ; LDS 48 KB -> 2 blocks/CU
__global__ __launch_bounds__(256)
void gemm_fused(const float* __restrict__ x, const float* __restrict__ W,
                const unsigned short* __restrict__ Mh, const unsigned short* __restrict__ Ml,
                const float* __restrict__ bias,
                float* __restrict__ partial, int* __restrict__ cnt,
                float* __restrict__ out) {
    const int bid   = blockIdx.x;
    const int kspl  = bid & 7;
    const int n_blk = (bid >> 3) & 3;
    const int m_blk = bid >> 5;
    const int row0 = m_blk * 64, n0 = n_blk * 128, k0 = kspl * 64;
    const int tid = threadIdx.x;
    const int lane = tid & 63, w = tid >> 6;
    const int wm = w >> 1, wn = w & 1;
    const int r15 = lane & 15, q = lane >> 4;

    __shared__ alignas(16) unsigned short sAh[64 * 64];
    __shared__ alignas(16) unsigned short sAl[64 * 64];
    __shared__ alignas(16) unsigned short sBh[128 * 64];
    __shared__ alignas(16) unsigned short sBl[128 * 64];
    __shared__ int lastFlag;

    // ---- A tile: convert x rows [row0,row0+64) x k-window directly into LDS hi/lo ----
    {
        const int row = tid >> 2;            // 0..63
        const int cb  = (tid & 3) * 2;       // chunk-of-8 base {0,2,4,6}
        const float* src = x + (size_t)(row0 + row) * DIM + k0;
        #pragma unroll
        for (int u = 0; u < 2; ++u) {
            const int c = cb + u;
            const float4 v0 = *(const float4*)(src + c * 8);
            const float4 v1 = *(const float4*)(src + c * 8 + 4);
            bf16x8 hv, lv;
            const float vs[8] = {v0.x, v0.y, v0.z, v0.w, v1.x, v1.y, v1.z, v1.w};
            #pragma unroll
            for (int e = 0; e < 8; ++e) {
                unsigned short h = f2bf(vs[e]);
                hv[e] = (short)h;
                lv[e] = (short)f2bf(vs[e] - bf2f(h));
            }
            const int loff = row * 64 + ((c ^ (row & 7)) * 8);
            *(bf16x8*)(sAh + loff) = hv;
            *(bf16x8*)(sAl + loff) = lv;
        }
    }
    // ---- B tile: Mh/Ml rows [n0,n0+128) x k-window, b128 coalesced + XOR-swizzled ----
    #pragma unroll
    for (int s = 0; s < 4; ++s) {
        const int p = tid + 256 * s;         // 0..1023
        const int row = p >> 3, c = p & 7;
        const int goff = (n0 + row) * DIM + k0 + c * 8;
        const int loff = row * 64 + ((c ^ (row & 7)) * 8);
        *(bf16x8*)(sBh + loff) = *(const bf16x8*)(Mh + goff);
        *(bf16x8*)(sBl + loff) = *(const bf16x8*)(Ml + goff);
    }
    __syncthreads();

    f32x4 acc[2][4];
    #pragma unroll
    for (int i = 0; i < 2; ++i)
        #pragma unroll
        for (int j = 0; j < 4; ++j) acc[i][j] = (f32x4){0.f, 0.f, 0.f, 0.f};

    #pragma unroll
    for (int ks = 0; ks < 2; ++ks) {
        const int c = ks * 4 + q;            // chunk-of-8 along k
        bf16x8 ah[2], al[2];
        #pragma unroll
        for (int sm = 0; sm < 2; ++sm) {
            const int row = wm * 32 + sm * 16 + r15;
            const int off = row * 64 + ((c ^ (row & 7)) * 8);
            ah[sm] = *(const bf16x8*)(sAh + off);
            al[sm] = *(const bf16x8*)(sAl + off);
        }
        #pragma unroll
        for (int sn = 0; sn < 4; ++sn) {
            const int row = wn * 64 + sn * 16 + r15;
            const int off = row * 64 + ((c ^ (row & 7)) * 8);
            const bf16x8 bh = *(const bf16x8*)(sBh + off);
            const bf16x8 bl = *(const bf16x8*)(sBl + off);
            acc[0][sn] = __builtin_amdgcn_mfma_f32_16x16x32_bf16(ah[0], bh, acc[0][sn], 0, 0, 0);
            acc[1][sn] = __builtin_amdgcn_mfma_f32_16x16x32_bf16(ah[1], bh, acc[1][sn], 0, 0, 0);
            acc[0][sn] = __builtin_amdgcn_mfma_f32_16x16x32_bf16(al[0], bh, acc[0][sn], 0, 0, 0);
            acc[1][sn] = __builtin_amdgcn_mfma_f32_16x16x32_bf16(al[1], bh, acc[1][sn], 0, 0, 0);
            acc[0][sn] = __builtin_amdgcn_mfma_f32_16x16x32_bf16(ah[0], bl, acc[0][sn], 0, 0, 0);
            acc[1][sn] = __builtin_amdgcn_mfma_f32_16x16x32_bf16(ah[1], bl, acc[1][sn], 0, 0, 0);
            acc[0][sn] = __builtin_amdgcn_mfma_f32_16x16x32_bf16(al[0], bl, acc[0][sn], 0, 0, 0);
            acc[1][sn] = __builtin_amdgcn_mfma_f32_16x16x32_bf16(al[1], bl, acc[1][sn], 0, 0, 0);
        }
    }

    // ---- fused epilogue: y_part[m] = sum_n (T[m][n] + (kspl==0 ? wl[n] : 0)) * x[m][n] ----
    float yl[2][4];
    #pragma unroll
    for (int i = 0; i < 2; ++i)
        #pragma unroll
        for (int r = 0; r < 4; ++r) yl[i][r] = 0.f;

    #pragma unroll
    for (int sn = 0; sn < 4; ++sn) {
        const int n = n0 + wn * 64 + sn * 16 + r15;
        const float wlv = (kspl == 0) ? W[n] : 0.f;
        #pragma unroll
        for (int sm = 0; sm < 2; ++sm) {
            const int mbase = row0 + wm * 32 + sm * 16 + q * 4;
            #pragma unroll
            for (int r = 0; r < 4; ++r) {
                const float xv = x[(size_t)(mbase + r) * DIM + n];
                yl[sm][r] += (acc[sm][sn][r] + wlv) * xv;
            }
        }
    }
    #pragma unroll
    for (int off = 1; off < 16; off <<= 1) {
        #pragma unroll
        for (int sm = 0; sm < 2; ++sm)
            #pragma unroll
            for (int r = 0; r < 4; ++r)
                yl[sm][r] += __shfl_xor(yl[sm][r], off);
    }
    const int slot = (n_blk * 2 + wn) * 8 + kspl;    // 0..63, unique per (block, wn)
    if (r15 == 0) {
        #pragma unroll
        for (int sm = 0; sm < 2; ++sm)
            #pragma unroll
            for (int r = 0; r < 4; ++r)
                partial[slot * BATCH + row0 + wm * 32 + sm * 16 + q * 4 + r] = yl[sm][r];
    }

    // ---- split-K fan-in: 32nd arriver per m_blk does the deterministic final sum ----
    __threadfence();                                  // release partials (device scope)
    __syncthreads();
    if (tid == 0) {
        const int old = atomicAdd(&cnt[m_blk], 1);
        lastFlag = (old == 31);
    }
    __syncthreads();
    if (lastFlag) {
        __threadfence();                              // acquire others' partials
        if (tid < 64) {
            float z = bias[0];
            #pragma unroll 16
            for (int s = 0; s < 64; ++s) z += partial[s * BATCH + row0 + tid];
            out[row0 + tid] = 1.0f / (1.0f + expf(-z));
        }
    }
}

extern "C" void kernel_launch(void* const* d_in, const int* in_sizes, int n_in,
                              void* d_out, int out_size, void* d_ws, size_t ws_size,
                              hipStream_t stream) {
    const float* x = (const float*)d_in[0];   // [1024, 512]
    const float* W = (const float*)d_in[1];   // [1, 131840]
    const float* b = (const float*)d_in[2];   // [1]
    float* out = (float*)d_out;               // [1024]

    unsigned short* Mh = (unsigned short*)d_ws;
    unsigned short* Ml = (unsigned short*)((char*)d_ws + ML_BYTE);
    float* partial     = (float*)((char*)d_ws + PART_BYTE);
    int* cnt           = (int*)((char*)d_ws + CNT_BYTE);

    hipLaunchKernelGGL(prep,       dim3(137), dim3(256), 0, stream, W, Mh, Ml, cnt);
    hipLaunchKernelGGL(gemm_fused, dim3(512), dim3(256), 0, stream, x, W, Mh, Ml, b,
                       partial, cnt, out);
}

// Round 6
// 15.106 us; speedup vs baseline: 4.0510x; 4.0510x over previous
//
#include <hip/hip_runtime.h>
#include <math.h>

#define DIM 512
#define BATCH 1024
#define NPAIR (DIM * (DIM - 1) / 2)

typedef short bf16x8 __attribute__((ext_vector_type(8)));
typedef float f32x4  __attribute__((ext_vector_type(4)));

// ---- bf16 split helpers (RTN-even) ----
__device__ __forceinline__ unsigned short f2bf(float f) {
    unsigned int u = __float_as_uint(f);
    u += 0x7fff + ((u >> 16) & 1);
    return (unsigned short)(u >> 16);
}
__device__ __forceinline__ float bf2f(unsigned short h) {
    return __uint_as_float(((unsigned int)h) << 16);
}

// ws: partial float[40][1024] at offset 0 (160 KB). slot = p*2 + wn.
// Upper-triangular U: U[k][n] = Wp[roff(k)+n] for n>k, Wsq[k] for n==k, 0 for n<k.
// roff(k) = k*(DIM-2) - k(k-1)/2 - 1 ; roff(k+1)-roff(k) = DIM-2-k.
// Tiles (n_blk, kspl) with k0 < n0+128 only: per n_blk {2,4,6,8} -> 20 tiles/m_blk.

// grid 320 = 16 m_blk x 20 tile-pairs ; block 256 thr = 4 waves (2 wm x 2 wn)
// block tile: 64 m x 128 n x 64 k ; wave 32m x 64n (2 sm x 4 sn of 16x16x32)
__global__ __launch_bounds__(256)
void quad_gemm(const float* __restrict__ x, const float* __restrict__ W,
               float* __restrict__ partial) {
    const int bid   = blockIdx.x;
    const int m_blk = bid / 20;
    const int p     = bid - m_blk * 20;
    const int n_blk = (p < 2) ? 0 : (p < 6) ? 1 : (p < 12) ? 2 : 3;
    const int kb    = (p < 2) ? 0 : (p < 6) ? 2 : (p < 12) ? 6 : 12;
    const int kspl  = p - kb;
    const int row0 = m_blk * 64, n0 = n_blk * 128, k0 = kspl * 64;

    const int tid = threadIdx.x;
    const int lane = tid & 63, w = tid >> 6;
    const int wm = w >> 1, wn = w & 1;
    const int r15 = lane & 15, q = lane >> 4;

    const float* Wp  = W + DIM;
    const float* Wsq = W + DIM + NPAIR;

    __shared__ alignas(16) unsigned short sAh[64 * 64];
    __shared__ alignas(16) unsigned short sAl[64 * 64];
    __shared__ alignas(16) unsigned short sBh[128 * 64];
    __shared__ alignas(16) unsigned short sBl[128 * 64];

    // ---- A tile: x rows [row0,row0+64) x k-window, hi/lo convert in-kernel ----
    {
        const int row = tid >> 2;                    // 0..63
        const float* src = x + (size_t)(row0 + row) * DIM + k0;
        #pragma unroll
        for (int u = 0; u < 2; ++u) {
            const int c = (tid & 3) + u * 4;         // 0..7, coalesced at fixed u
            const float4 v0 = *(const float4*)(src + c * 8);
            const float4 v1 = *(const float4*)(src + c * 8 + 4);
            const float vs[8] = {v0.x, v0.y, v0.z, v0.w, v1.x, v1.y, v1.z, v1.w};
            bf16x8 hv, lv;
            #pragma unroll
            for (int e = 0; e < 8; ++e) {
                unsigned short h = f2bf(vs[e]);
                hv[e] = (short)h;
                lv[e] = (short)f2bf(vs[e] - bf2f(h));
            }
            const int loff = row * 64 + ((c ^ (row & 7)) * 8);
            *(bf16x8*)(sAh + loff) = hv;
            *(bf16x8*)(sAl + loff) = lv;
        }
    }

    // ---- B tile: U[k][n] gathered from packed triangle; sB[n-row][k] ----
    {
        const int nr = tid & 127;                    // LDS row (n - n0)
        const int n  = n0 + nr;
        const int cb = (tid >> 7) * 4;               // chunk base {0,4}
        #pragma unroll
        for (int u = 0; u < 4; ++u) {
            const int c = cb + u;                    // k-chunk 0..7
            float vs[8];
            int k  = k0 + c * 8;
            int ro = k * (DIM - 2) - (k * (k - 1)) / 2 - 1;   // roff(k)
            #pragma unroll
            for (int e = 0; e < 8; ++e) {
                const float wv = Wp[ro + n];         // coalesced across lanes (contig n)
                vs[e] = (n > k) ? wv : ((n == k) ? Wsq[k] : 0.f);
                ro += DIM - 2 - k;                   // roff(k+1)
                ++k;
            }
            bf16x8 hv, lv;
            #pragma unroll
            for (int e = 0; e < 8; ++e) {
                unsigned short h = f2bf(vs[e]);
                hv[e] = (short)h;
                lv[e] = (short)f2bf(vs[e] - bf2f(h));
            }
            const int loff = nr * 64 + ((c ^ (nr & 7)) * 8);
            *(bf16x8*)(sBh + loff) = hv;
            *(bf16x8*)(sBl + loff) = lv;
        }
    }
    __syncthreads();

    // ---- 3-term bf16-split MFMA: T = Xh*Uh + Xl*Uh + Xh*Ul ----
    f32x4 acc[2][4];
    #pragma unroll
    for (int i = 0; i < 2; ++i)
        #pragma unroll
        for (int j = 0; j < 4; ++j) acc[i][j] = (f32x4){0.f, 0.f, 0.f, 0.f};

    #pragma unroll
    for (int ks = 0; ks < 2; ++ks) {
        const int c = ks * 4 + q;                    // chunk-of-8 along k
        bf16x8 ah[2], al[2];
        #pragma unroll
        for (int sm = 0; sm < 2; ++sm) {
            const int row = wm * 32 + sm * 16 + r15;
            const int off = row * 64 + ((c ^ (row & 7)) * 8);
            ah[sm] = *(const bf16x8*)(sAh + off);
            al[sm] = *(const bf16x8*)(sAl + off);
        }
        #pragma unroll
        for (int sn = 0; sn < 4; ++sn) {
            const int row = wn * 64 + sn * 16 + r15;
            const int off = row * 64 + ((c ^ (row & 7)) * 8);
            const bf16x8 bh = *(const bf16x8*)(sBh + off);
            const bf16x8 bl = *(const bf16x8*)(sBl + off);
            acc[0][sn] = __builtin_amdgcn_mfma_f32_16x16x32_bf16(ah[0], bh, acc[0][sn], 0, 0, 0);
            acc[1][sn] = __builtin_amdgcn_mfma_f32_16x16x32_bf16(ah[1], bh, acc[1][sn], 0, 0, 0);
            acc[0][sn] = __builtin_amdgcn_mfma_f32_16x16x32_bf16(al[0], bh, acc[0][sn], 0, 0, 0);
            acc[1][sn] = __builtin_amdgcn_mfma_f32_16x16x32_bf16(al[1], bh, acc[1][sn], 0, 0, 0);
            acc[0][sn] = __builtin_amdgcn_mfma_f32_16x16x32_bf16(ah[0], bl, acc[0][sn], 0, 0, 0);
            acc[1][sn] = __builtin_amdgcn_mfma_f32_16x16x32_bf16(ah[1], bl, acc[1][sn], 0, 0, 0);
        }
    }

    // ---- fused epilogue: y_part[m] = sum_n (T[m][n] + (kspl==0 ? Wlin[n] : 0)) * x[m][n] ----
    float yl[2][4];
    #pragma unroll
    for (int i = 0; i < 2; ++i)
        #pragma unroll
        for (int r = 0; r < 4; ++r) yl[i][r] = 0.f;

    #pragma unroll
    for (int sn = 0; sn < 4; ++sn) {
        const int n = n0 + wn * 64 + sn * 16 + r15;
        const float wlv = (kspl == 0) ? W[n] : 0.f;
        #pragma unroll
        for (int sm = 0; sm < 2; ++sm) {
            const int mbase = row0 + wm * 32 + sm * 16 + q * 4;
            #pragma unroll
            for (int r = 0; r < 4; ++r) {
                const float xv = x[(size_t)(mbase + r) * DIM + n];
                yl[sm][r] += (acc[sm][sn][r] + wlv) * xv;
            }
        }
    }
    #pragma unroll
    for (int off = 1; off < 16; off <<= 1) {
        #pragma unroll
        for (int sm = 0; sm < 2; ++sm)
            #pragma unroll
            for (int r = 0; r < 4; ++r)
                yl[sm][r] += __shfl_xor(yl[sm][r], off);
    }
    const int slot = p * 2 + wn;                     // 0..39, unique per (tile, wn)
    if (r15 == 0) {
        #pragma unroll
        for (int sm = 0; sm < 2; ++sm)
            #pragma unroll
            for (int r = 0; r < 4; ++r)
                partial[(size_t)slot * BATCH + row0 + wm * 32 + sm * 16 + q * 4 + r] = yl[sm][r];
    }
}

// ---- finalize: fixed-order sum of 40 slots + bias, sigmoid (no fences needed:
// dispatch boundary on the stream orders gemm's stores before these loads) ----
__global__ __launch_bounds__(256)
void finalize(const float* __restrict__ partial, const float* __restrict__ bias,
              float* __restrict__ out) {
    const int t = blockIdx.x * 256 + threadIdx.x;
    float z = bias[0];
    #pragma unroll 8
    for (int s = 0; s < 40; ++s) z += partial[(size_t)s * BATCH + t];
    out[t] = 1.0f / (1.0f + expf(-z));
}

extern "C" void kernel_launch(void* const* d_in, const int* in_sizes, int n_in,
                              void* d_out, int out_size, void* d_ws, size_t ws_size,
                              hipStream_t stream) {
    const float* x = (const float*)d_in[0];   // [1024, 512]
    const float* W = (const float*)d_in[1];   // [1, 131840]
    const float* b = (const float*)d_in[2];   // [1]
    float* out = (float*)d_out;               // [1024]

    float* partial = (float*)d_ws;            // 40*1024 floats, fully rewritten each call

    hipLaunchKernelGGL(quad_gemm, dim3(320), dim3(256), 0, stream, x, W, partial);
    hipLaunchKernelGGL(finalize,  dim3(BATCH / 256), dim3(256), 0, stream, partial, b, out);
}

// Round 9
// 13.334 us; speedup vs baseline: 4.5897x; 1.1330x over previous
//
#include <hip/hip_runtime.h>
#include <math.h>

#define DIM 512
#define BATCH 1024
#define NPAIR (DIM * (DIM - 1) / 2)
#define TPB 512

typedef short bf16x8 __attribute__((ext_vector_type(8)));
typedef float f32x4  __attribute__((ext_vector_type(4)));

// ---- bf16 split helpers (RTN-even) ----
__device__ __forceinline__ unsigned short f2bf(float f) {
    unsigned int u = __float_as_uint(f);
    u += 0x7fff + ((u >> 16) & 1);
    return (unsigned short)(u >> 16);
}
__device__ __forceinline__ float bf2f(unsigned short h) {
    return __uint_as_float(((unsigned int)h) << 16);
}

// ws: partial float[20][1024] (80 KB). slot = p (one per tile-block).
// Upper-triangular U: U[k][n] = Wp[roff(k)+n] for n>k, Wsq[k] for n==k, 0 for n<k.
// roff(k) = k*(DIM-2) - k(k-1)/2 - 1 ; roff(k+1)-roff(k) = DIM-2-k.
// Tile list per n_blk: {2,4,6,8} k-windows -> 20 tiles per m_blk.

// grid 320 = 16 m_blk x 20 p ; block 512 thr = 8 waves (2 wm x 4 wn)
// block tile: 64 m x 128 n x 64 k ; wave 32m x 32n (2 sm x 2 sn of 16x16x32)
__global__ __launch_bounds__(TPB)
void quad_gemm(const float* __restrict__ x, const float* __restrict__ W,
               float* __restrict__ partial) {
    const int bid   = blockIdx.x;
    const int m_blk = bid / 20;
    const int p     = bid - m_blk * 20;
    const int n_blk = (p < 2) ? 0 : (p < 6) ? 1 : (p < 12) ? 2 : 3;
    const int kb    = (p < 2) ? 0 : (p < 6) ? 2 : (p < 12) ? 6 : 12;
    const int kspl  = p - kb;
    const int row0 = m_blk * 64, n0 = n_blk * 128, k0 = kspl * 64;

    const int tid = threadIdx.x;
    const int lane = tid & 63, w = tid >> 6;   // 8 waves
    const int wm = w >> 2, wn = w & 3;
    const int r15 = lane & 15, q = lane >> 4;

    const float* Wp  = W + DIM;
    const float* Wsq = W + DIM + NPAIR;

    __shared__ alignas(16) unsigned short sAh[64 * 64];
    __shared__ alignas(16) unsigned short sAl[64 * 64];
    __shared__ alignas(16) unsigned short sBh[128 * 64];
    __shared__ alignas(16) unsigned short sBl[128 * 64];
    __shared__ float ysum[4][64];              // [wn][m-in-block]

    // ---- A tile: x rows [row0,row0+64) x k-window; 8 el/thread ----
    {
        const int row = tid >> 3;              // 0..63
        const int c   = tid & 7;               // k-chunk 0..7
        const float* src = x + (size_t)(row0 + row) * DIM + k0 + c * 8;
        const float4 v0 = *(const float4*)(src);
        const float4 v1 = *(const float4*)(src + 4);
        const float vs[8] = {v0.x, v0.y, v0.z, v0.w, v1.x, v1.y, v1.z, v1.w};
        bf16x8 hv, lv;
        #pragma unroll
        for (int e = 0; e < 8; ++e) {
            unsigned short h = f2bf(vs[e]);
            hv[e] = (short)h;
            lv[e] = (short)f2bf(vs[e] - bf2f(h));
        }
        const int loff = row * 64 + ((c ^ (row & 7)) * 8);
        *(bf16x8*)(sAh + loff) = hv;
        *(bf16x8*)(sAl + loff) = lv;
    }

    // ---- B tile: U[k][n] gathered from packed triangle; 16 el/thread ----
    {
        const int nr = tid & 127;              // LDS row (n - n0)
        const int n  = n0 + nr;
        const int cb = (tid >> 7) * 2;         // chunk base {0,2,4,6}
        #pragma unroll
        for (int u = 0; u < 2; ++u) {
            const int c = cb + u;              // k-chunk 0..7
            float vs[8];
            int k  = k0 + c * 8;
            int ro = k * (DIM - 2) - (k * (k - 1)) / 2 - 1;   // roff(k)
            #pragma unroll
            for (int e = 0; e < 8; ++e) {
                const float wv = Wp[ro + n];   // coalesced across lanes (contig n)
                vs[e] = (n > k) ? wv : ((n == k) ? Wsq[k] : 0.f);
                ro += DIM - 2 - k;
                ++k;
            }
            bf16x8 hv, lv;
            #pragma unroll
            for (int e = 0; e < 8; ++e) {
                unsigned short h = f2bf(vs[e]);
                hv[e] = (short)h;
                lv[e] = (short)f2bf(vs[e] - bf2f(h));
            }
            const int loff = nr * 64 + ((c ^ (nr & 7)) * 8);
            *(bf16x8*)(sBh + loff) = hv;
            *(bf16x8*)(sBl + loff) = lv;
        }
    }

    // ---- prefetch epilogue operands (latency hides under barrier + MFMA) ----
    float xv[2][2][4];                          // [sn][sm][r]
    float wlv[2];
    #pragma unroll
    for (int sn = 0; sn < 2; ++sn) {
        const int n = n0 + wn * 32 + sn * 16 + r15;
        wlv[sn] = (kspl == 0) ? W[n] : 0.f;
        #pragma unroll
        for (int sm = 0; sm < 2; ++sm) {
            const int mbase = row0 + wm * 32 + sm * 16 + q * 4;
            #pragma unroll
            for (int r = 0; r < 4; ++r)
                xv[sn][sm][r] = x[(size_t)(mbase + r) * DIM + n];
        }
    }
    __syncthreads();

    // ---- 3-term bf16-split MFMA: T = Xh*Uh + Xl*Uh + Xh*Ul ----
    f32x4 acc[2][2];
    #pragma unroll
    for (int i = 0; i < 2; ++i)
        #pragma unroll
        for (int j = 0; j < 2; ++j) acc[i][j] = (f32x4){0.f, 0.f, 0.f, 0.f};

    #pragma unroll
    for (int ks = 0; ks < 2; ++ks) {
        const int c = ks * 4 + q;              // chunk-of-8 along k
        bf16x8 ah[2], al[2];
        #pragma unroll
        for (int sm = 0; sm < 2; ++sm) {
            const int row = wm * 32 + sm * 16 + r15;
            const int off = row * 64 + ((c ^ (row & 7)) * 8);
            ah[sm] = *(const bf16x8*)(sAh + off);
            al[sm] = *(const bf16x8*)(sAl + off);
        }
        #pragma unroll
        for (int sn = 0; sn < 2; ++sn) {
            const int row = wn * 32 + sn * 16 + r15;
            const int off = row * 64 + ((c ^ (row & 7)) * 8);
            const bf16x8 bh = *(const bf16x8*)(sBh + off);
            const bf16x8 bl = *(const bf16x8*)(sBl + off);
            acc[0][sn] = __builtin_amdgcn_mfma_f32_16x16x32_bf16(ah[0], bh, acc[0][sn], 0, 0, 0);
            acc[1][sn] = __builtin_amdgcn_mfma_f32_16x16x32_bf16(ah[1], bh, acc[1][sn], 0, 0, 0);
            acc[0][sn] = __builtin_amdgcn_mfma_f32_16x16x32_bf16(al[0], bh, acc[0][sn], 0, 0, 0);
            acc[1][sn] = __builtin_amdgcn_mfma_f32_16x16x32_bf16(al[1], bh, acc[1][sn], 0, 0, 0);
            acc[0][sn] = __builtin_amdgcn_mfma_f32_16x16x32_bf16(ah[0], bl, acc[0][sn], 0, 0, 0);
            acc[1][sn] = __builtin_amdgcn_mfma_f32_16x16x32_bf16(ah[1], bl, acc[1][sn], 0, 0, 0);
        }
    }

    // ---- fused epilogue: y_part[m] = sum_n (T + Wlin?) * x ----
    float yl[2][4];
    #pragma unroll
    for (int sm = 0; sm < 2; ++sm)
        #pragma unroll
        for (int r = 0; r < 4; ++r) yl[sm][r] = 0.f;

    #pragma unroll
    for (int sn = 0; sn < 2; ++sn)
        #pragma unroll
        for (int sm = 0; sm < 2; ++sm)
            #pragma unroll
            for (int r = 0; r < 4; ++r)
                yl[sm][r] += (acc[sm][sn][r] + wlv[sn]) * xv[sn][sm][r];

    #pragma unroll
    for (int off = 1; off < 16; off <<= 1) {
        #pragma unroll
        for (int sm = 0; sm < 2; ++sm)
            #pragma unroll
            for (int r = 0; r < 4; ++r)
                yl[sm][r] += __shfl_xor(yl[sm][r], off);
    }
    if (r15 == 0) {
        #pragma unroll
        for (int sm = 0; sm < 2; ++sm)
            #pragma unroll
            for (int r = 0; r < 4; ++r)
                ysum[wn][wm * 32 + sm * 16 + q * 4 + r] = yl[sm][r];
    }
    __syncthreads();
    if (tid < 64) {
        const float z = (ysum[0][tid] + ysum[1][tid]) + (ysum[2][tid] + ysum[3][tid]);
        partial[(size_t)p * BATCH + row0 + tid] = z;
    }
}

// ---- finalize: fixed-order sum of 20 slots + bias, sigmoid ----
__global__ __launch_bounds__(256)
void finalize(const float* __restrict__ partial, const float* __restrict__ bias,
              float* __restrict__ out) {
    const int t = blockIdx.x * 256 + threadIdx.x;
    float z = bias[0];
    #pragma unroll
    for (int s = 0; s < 20; ++s) z += partial[(size_t)s * BATCH + t];
    out[t] = 1.0f / (1.0f + expf(-z));
}

extern "C" void kernel_launch(void* const* d_in, const int* in_sizes, int n_in,
                              void* d_out, int out_size, void* d_ws, size_t ws_size,
                              hipStream_t stream) {
    const float* x = (const float*)d_in[0];   // [1024, 512]
    const float* W = (const float*)d_in[1];   // [1, 131840]
    const float* b = (const float*)d_in[2];   // [1]
    float* out = (float*)d_out;               // [1024]

    float* partial = (float*)d_ws;            // 20*1024 floats, fully rewritten each call

    hipLaunchKernelGGL(quad_gemm, dim3(320), dim3(TPB), 0, stream, x, W, partial);
    hipLaunchKernelGGL(finalize,  dim3(BATCH / 256), dim3(256), 0, stream, partial, b, out);
}

// Round 10
// 12.806 us; speedup vs baseline: 4.7788x; 1.0412x over previous
//
#include <hip/hip_runtime.h>
#include <math.h>

#define DIM 512
#define BATCH 1024
#define NPAIR (DIM * (DIM - 1) / 2)
#define TPB 512

typedef short bf16x8 __attribute__((ext_vector_type(8)));
typedef float f32x4  __attribute__((ext_vector_type(4)));

// ---- bf16 split helpers (RTN-even) ----
__device__ __forceinline__ unsigned short f2bf(float f) {
    unsigned int u = __float_as_uint(f);
    u += 0x7fff + ((u >> 16) & 1);
    return (unsigned short)(u >> 16);
}
__device__ __forceinline__ float bf2f(unsigned short h) {
    return __uint_as_float(((unsigned int)h) << 16);
}

// ws: partial float[20][1024] (80 KB). slot = p.
// Upper-triangular U: U[k][n] = Wp[roff(k)+n] for n>k, Wsq[k] for n==k, 0 for n<k.
// roff(k) = k*(DIM-2) - k(k-1)/2 - 1 ; roff(k+1)-roff(k) = DIM-2-k.
// Tile list per 128-row group: n_blk {0,1,2,3} x kwin {2,4,6,8} -> 20 tiles.

// grid 160 = 8 mg x 20 p ; block 512 thr = 8 waves (4 wm x 2 wn) -> 1 block/CU, 1 round
// block tile: 128 m x 128 n x 64 k ; wave 32m x 64n (2 sm x 4 sn of 16x16x32)
__global__ __launch_bounds__(TPB, 2)
void quad_gemm(const float* __restrict__ x, const float* __restrict__ W,
               float* __restrict__ partial) {
    const int bid = blockIdx.x;
    const int mg  = bid / 20;                  // row-group 0..7 (128 rows)
    const int p   = bid - mg * 20;
    const int n_blk = (p < 2) ? 0 : (p < 6) ? 1 : (p < 12) ? 2 : 3;
    const int kb    = (p < 2) ? 0 : (p < 6) ? 2 : (p < 12) ? 6 : 12;
    const int kspl  = p - kb;
    const int row0 = mg * 128, n0 = n_blk * 128, k0 = kspl * 64;

    const int tid = threadIdx.x;
    const int lane = tid & 63, w = tid >> 6;   // 8 waves
    const int wm = w >> 1, wn = w & 1;         // 4 x 2
    const int r15 = lane & 15, q = lane >> 4;

    const float* Wp  = W + DIM;
    const float* Wsq = W + DIM + NPAIR;

    __shared__ alignas(16) unsigned short sAh[128 * 64];
    __shared__ alignas(16) unsigned short sAl[128 * 64];
    __shared__ alignas(16) unsigned short sBh[128 * 64];
    __shared__ alignas(16) unsigned short sBl[128 * 64];
    __shared__ float ysum[2][128];             // [wn][m-in-block]

    // ---- A tile: x rows [row0,row0+128) x k-window; 16 el/thread ----
    #pragma unroll
    for (int u = 0; u < 2; ++u) {
        const int row = (tid >> 3) + u * 64;   // 0..127
        const int c   = tid & 7;               // k-chunk 0..7
        const float* src = x + (size_t)(row0 + row) * DIM + k0 + c * 8;
        const float4 v0 = *(const float4*)(src);
        const float4 v1 = *(const float4*)(src + 4);
        const float vs[8] = {v0.x, v0.y, v0.z, v0.w, v1.x, v1.y, v1.z, v1.w};
        bf16x8 hv, lv;
        #pragma unroll
        for (int e = 0; e < 8; ++e) {
            unsigned short h = f2bf(vs[e]);
            hv[e] = (short)h;
            lv[e] = (short)f2bf(vs[e] - bf2f(h));
        }
        const int loff = row * 64 + ((c ^ (row & 7)) * 8);
        *(bf16x8*)(sAh + loff) = hv;
        *(bf16x8*)(sAl + loff) = lv;
    }

    // ---- B tile: U[k][n] gathered from packed triangle; 16 el/thread ----
    {
        const int nr = tid & 127;              // LDS row (n - n0)
        const int n  = n0 + nr;
        const int cb = (tid >> 7) * 2;         // chunk base {0,2,4,6}
        #pragma unroll
        for (int u = 0; u < 2; ++u) {
            const int c = cb + u;              // k-chunk 0..7
            float vs[8];
            int k  = k0 + c * 8;
            int ro = k * (DIM - 2) - (k * (k - 1)) / 2 - 1;   // roff(k)
            #pragma unroll
            for (int e = 0; e < 8; ++e) {
                const float wv = Wp[ro + n];   // coalesced across lanes (contig n)
                vs[e] = (n > k) ? wv : ((n == k) ? Wsq[k] : 0.f);
                ro += DIM - 2 - k;
                ++k;
            }
            bf16x8 hv, lv;
            #pragma unroll
            for (int e = 0; e < 8; ++e) {
                unsigned short h = f2bf(vs[e]);
                hv[e] = (short)h;
                lv[e] = (short)f2bf(vs[e] - bf2f(h));
            }
            const int loff = nr * 64 + ((c ^ (nr & 7)) * 8);
            *(bf16x8*)(sBh + loff) = hv;
            *(bf16x8*)(sBl + loff) = lv;
        }
    }

    // ---- prefetch epilogue operands (latency hides under barrier + MFMA) ----
    float xv[4][2][4];                          // [sn][sm][r]
    float wlv[4];
    #pragma unroll
    for (int sn = 0; sn < 4; ++sn) {
        const int n = n0 + wn * 64 + sn * 16 + r15;
        wlv[sn] = (kspl == 0) ? W[n] : 0.f;
        #pragma unroll
        for (int sm = 0; sm < 2; ++sm) {
            const int mbase = row0 + wm * 32 + sm * 16 + q * 4;
            #pragma unroll
            for (int r = 0; r < 4; ++r)
                xv[sn][sm][r] = x[(size_t)(mbase + r) * DIM + n];
        }
    }
    __syncthreads();

    // ---- 3-term bf16-split MFMA: T = Xh*Uh + Xl*Uh + Xh*Ul ----
    f32x4 acc[2][4];                            // [sm][sn]
    #pragma unroll
    for (int i = 0; i < 2; ++i)
        #pragma unroll
        for (int j = 0; j < 4; ++j) acc[i][j] = (f32x4){0.f, 0.f, 0.f, 0.f};

    #pragma unroll
    for (int ks = 0; ks < 2; ++ks) {
        const int c = ks * 4 + q;              // chunk-of-8 along k
        bf16x8 ah[2], al[2];
        #pragma unroll
        for (int sm = 0; sm < 2; ++sm) {
            const int row = wm * 32 + sm * 16 + r15;
            const int off = row * 64 + ((c ^ (row & 7)) * 8);
            ah[sm] = *(const bf16x8*)(sAh + off);
            al[sm] = *(const bf16x8*)(sAl + off);
        }
        #pragma unroll
        for (int sn = 0; sn < 4; ++sn) {
            const int row = wn * 64 + sn * 16 + r15;
            const int off = row * 64 + ((c ^ (row & 7)) * 8);
            const bf16x8 bh = *(const bf16x8*)(sBh + off);
            const bf16x8 bl = *(const bf16x8*)(sBl + off);
            acc[0][sn] = __builtin_amdgcn_mfma_f32_16x16x32_bf16(ah[0], bh, acc[0][sn], 0, 0, 0);
            acc[1][sn] = __builtin_amdgcn_mfma_f32_16x16x32_bf16(ah[1], bh, acc[1][sn], 0, 0, 0);
            acc[0][sn] = __builtin_amdgcn_mfma_f32_16x16x32_bf16(al[0], bh, acc[0][sn], 0, 0, 0);
            acc[1][sn] = __builtin_amdgcn_mfma_f32_16x16x32_bf16(al[1], bh, acc[1][sn], 0, 0, 0);
            acc[0][sn] = __builtin_amdgcn_mfma_f32_16x16x32_bf16(ah[0], bl, acc[0][sn], 0, 0, 0);
            acc[1][sn] = __builtin_amdgcn_mfma_f32_16x16x32_bf16(ah[1], bl, acc[1][sn], 0, 0, 0);
        }
    }

    // ---- fused epilogue: y_part[m] = sum_n (T + Wlin?) * x ----
    float yl[2][4];
    #pragma unroll
    for (int sm = 0; sm < 2; ++sm)
        #pragma unroll
        for (int r = 0; r < 4; ++r) yl[sm][r] = 0.f;

    #pragma unroll
    for (int sn = 0; sn < 4; ++sn)
        #pragma unroll
        for (int sm = 0; sm < 2; ++sm)
            #pragma unroll
            for (int r = 0; r < 4; ++r)
                yl[sm][r] += (acc[sm][sn][r] + wlv[sn]) * xv[sn][sm][r];

    #pragma unroll
    for (int off = 1; off < 16; off <<= 1) {
        #pragma unroll
        for (int sm = 0; sm < 2; ++sm)
            #pragma unroll
            for (int r = 0; r < 4; ++r)
                yl[sm][r] += __shfl_xor(yl[sm][r], off);
    }
    if (r15 == 0) {
        #pragma unroll
        for (int sm = 0; sm < 2; ++sm)
            #pragma unroll
            for (int r = 0; r < 4; ++r)
                ysum[wn][wm * 32 + sm * 16 + q * 4 + r] = yl[sm][r];
    }
    __syncthreads();
    if (tid < 128) {
        const float z = ysum[0][tid] + ysum[1][tid];
        partial[(size_t)p * BATCH + row0 + tid] = z;
    }
}

// ---- finalize: fixed tree-sum of 20 slots + bias, sigmoid; 16 blocks for latency ----
__global__ __launch_bounds__(64)
void finalize(const float* __restrict__ partial, const float* __restrict__ bias,
              float* __restrict__ out) {
    const int t = blockIdx.x * 64 + threadIdx.x;
    float v[20];
    #pragma unroll
    for (int s = 0; s < 20; ++s) v[s] = partial[(size_t)s * BATCH + t];
    float z = (((v[0] + v[1]) + (v[2] + v[3])) + ((v[4] + v[5]) + (v[6] + v[7]))) +
              (((v[8] + v[9]) + (v[10] + v[11])) + ((v[12] + v[13]) + (v[14] + v[15]))) +
              ((v[16] + v[17]) + (v[18] + v[19])) + bias[0];
    out[t] = 1.0f / (1.0f + expf(-z));
}

extern "C" void kernel_launch(void* const* d_in, const int* in_sizes, int n_in,
                              void* d_out, int out_size, void* d_ws, size_t ws_size,
                              hipStream_t stream) {
    const float* x = (const float*)d_in[0];   // [1024, 512]
    const float* W = (const float*)d_in[1];   // [1, 131840]
    const float* b = (const float*)d_in[2];   // [1]
    float* out = (float*)d_out;               // [1024]

    float* partial = (float*)d_ws;            // 20*1024 floats, fully rewritten each call

    hipLaunchKernelGGL(quad_gemm, dim3(160), dim3(TPB), 0, stream, x, W, partial);
    hipLaunchKernelGGL(finalize,  dim3(BATCH / 64), dim3(64), 0, stream, partial, b, out);
}